// Round 8
// baseline (3909.232 us; speedup 1.0000x reference)
//
#include <hip/hip_runtime.h>
#include <stdint.h>

typedef unsigned long long u64;

#define NB 8
#define NPTS 4096
#define NC 64
#define KOUT 16
#define TSEL 48            // preselect size (top-48 contains true top-32)
#define CHUNK 128
#define NCHUNK (NPTS / CHUNK)
#define RPW 8              // rows per wave
#define RPB 32             // rows per block (4 waves)
#define BPB (NPTS / RPB)   // blocks per batch = 128

// sq[p]: 8 accumulator chains over stride-8, separate mul/add roundings,
// combined ((r0+r1)+(r2+r3))+((r4+r5)+(r6+r7)).
// DO NOT CHANGE: verified bitwise model of the harness reference (R6 pass).
__global__ __launch_bounds__(256) void sq_kernel(const float* __restrict__ pts,
                                                 float* __restrict__ sqw) {
    int p = blockIdx.x * 256 + threadIdx.x;
    const float* r = pts + (size_t)p * NC;
    float acc[8];
#pragma unroll
    for (int j = 0; j < 8; ++j) acc[j] = __fmul_rn(r[j], r[j]);
#pragma unroll
    for (int i = 8; i < 64; i += 8)
#pragma unroll
        for (int j = 0; j < 8; ++j)
            acc[j] = __fadd_rn(acc[j], __fmul_rn(r[i + j], r[i + j]));
    float s01 = __fadd_rn(acc[0], acc[1]);
    float s23 = __fadd_rn(acc[2], acc[3]);
    float s45 = __fadd_rn(acc[4], acc[5]);
    float s67 = __fadd_rn(acc[6], acc[7]);
    sqw[p] = __fadd_rn(__fadd_rn(s01, s23), __fadd_rn(s45, s67));
}

// Ascending sorted 64-slot list, one u32/lane: (keybits & 0xFFFFF000) | idx.
// Threshold slot 47 (48th smallest). Stale-threshold over-insertion is safe
// (superset). 20-bit key quantization (~0.03) << rank-32->48 gap (>0.8).
__device__ __forceinline__ void insert32(unsigned& list, unsigned cand, int lane) {
    unsigned thr = __shfl(list, 47);
    u64 mask = __ballot(cand < thr);
    while (mask) {
        int src = __ffsll(mask) - 1;
        unsigned v = __shfl(cand, src);
        int pos = __popcll(__ballot(list < v));
        unsigned up = __shfl_up(list, 1);
        list = (lane < pos) ? list : ((lane == pos) ? v : up);
        mask &= (mask - 1);
    }
}

// Exact re-rank of the 48 preselected candidates by the verified reference
// key: inner = ONE sequential FMA chain k=0..63 ascending (x operand uniform);
// key = fl(fl(sq_n - fl(2*inner)) + sq_m); ties by index. DO NOT CHANGE.
__device__ __forceinline__ void epilogue(unsigned list, int n, int b, int lane,
                                         const float* __restrict__ pb,
                                         const float* __restrict__ sqb,
                                         float sqn,
                                         const float* __restrict__ xyz,
                                         float* __restrict__ out) {
    int m = (int)(list & 0xFFFu);
    const float4* yr = (const float4*)(pb + (size_t)m * NC);
    float4 yv[16];
#pragma unroll
    for (int i = 0; i < 16; ++i) yv[i] = yr[i];
    const float* xr = pb + (size_t)n * NC;   // wave-uniform -> scalar loads
    const float* yf = (const float*)yv;
    float acc = 0.f;
#pragma unroll
    for (int k = 0; k < 64; ++k) acc = __fmaf_rn(xr[k], yf[k], acc);
    float key = __fadd_rn(__fsub_rn(sqn, __fmul_rn(2.0f, acc)), sqb[m]);

    int rank = 0;
#pragma unroll 1
    for (int j = 0; j < TSEL; ++j) {
        float kj = __shfl(key, j);
        int mj = __shfl(m, j);
        bool less = (kj < key) || (kj == key && mj < m);   // stable: lower idx first
        rank += less ? 1 : 0;
    }
    if (lane < TSEL && rank < 2 * KOUT && (rank & 1) == 0) {  // dilation D=2
        int k = rank >> 1;
        const float* xn = xyz + ((size_t)b * NPTS + n) * 3;
        const float* xm = xyz + ((size_t)b * NPTS + m) * 3;
        float xnx = xn[0], xny = xn[1], xnz = xn[2];
        float ox = xm[0], oy = xm[1], oz = xm[2];
        float rx = xnx - ox, ry = xny - oy, rz = xnz - oz;
        float dis = sqrtf(rx * rx + ry * ry + rz * rz);
        float* o = out + (((size_t)b * NPTS + n) * KOUT + k) * 10;
        o[0] = dis; o[1] = rx; o[2] = ry; o[3] = rz;
        o[4] = xnx; o[5] = xny; o[6] = xnz;
        o[7] = ox;  o[8] = oy;  o[9] = oz;
    }
}

// lane |-> candidate; x rows are wave-uniform scalar (SGPR) operands from
// global; y tile XOR-swizzled in LDS (phys slot = logical ^ (row & 15)) so
// per-8-lane phases hit distinct bank quads. 8 rows/wave share each y read.
__global__ __launch_bounds__(256)
void knn_kernel(const float* __restrict__ xyz,
                const float* __restrict__ pts,
                const float* __restrict__ sqw,
                float* __restrict__ out) {

    __shared__ float4 ylds[CHUNK * 16];   // 32 KB

    const int tid = threadIdx.x;
    const int lane = tid & 63;
    const int wave = tid >> 6;
    const int sw = lane & 15;
    const int b = blockIdx.x >> 7;                       // 128 blocks per batch
    const int rowbase = ((blockIdx.x & 127) << 5) + wave * RPW;
    const float* pb = pts + (size_t)b * NPTS * NC;
    const float* sqb = sqw + (size_t)b * NPTS;

    float sqn[RPW];                                      // uniform -> SGPRs
#pragma unroll
    for (int r = 0; r < RPW; ++r) sqn[r] = sqb[rowbase + r];

    unsigned list[RPW];
#pragma unroll
    for (int r = 0; r < RPW; ++r) list[r] = 0xFFFFFFFFu;

    const float4* gsrc = (const float4*)pb;
    float4 pf[8];
#pragma unroll
    for (int j = 0; j < 8; ++j) pf[j] = gsrc[tid + 256 * j];   // prefetch chunk 0

    for (int c = 0; c < NCHUNK; ++c) {
        __syncthreads();   // previous chunk fully consumed
#pragma unroll
        for (int j = 0; j < 8; ++j) {
            int s = tid + 256 * j;
            int ml = s >> 4;
            int c4 = s & 15;
            ylds[ml * 16 + (c4 ^ (ml & 15))] = pf[j];   // swizzled store
        }
        __syncthreads();
        if (c + 1 < NCHUNK) {
#pragma unroll
            for (int j = 0; j < 8; ++j)
                pf[j] = gsrc[(size_t)(c + 1) * (CHUNK * 16) + tid + 256 * j];
        }
#pragma unroll
        for (int sc = 0; sc < 2; ++sc) {
            const int crow = sc * 64 + lane;
            const int m = c * CHUNK + crow;
            const float sqm = sqb[m];                    // coalesced
            const float4* yrow = &ylds[crow * 16];
            float acc[RPW];
#pragma unroll
            for (int r = 0; r < RPW; ++r) acc[r] = 0.f;
#pragma unroll
            for (int h = 0; h < 2; ++h) {                // k-halves of 32
                float4 yh[8];
#pragma unroll
                for (int g = 0; g < 8; ++g) yh[g] = yrow[(h * 8 + g) ^ sw];
#pragma unroll
                for (int r = 0; r < RPW; ++r) {
                    const float* xr = pb + (size_t)(rowbase + r) * NC + h * 32;
                    float a = acc[r];
#pragma unroll
                    for (int g = 0; g < 8; ++g) {        // x uniform: SGPR src
                        a = fmaf(xr[4 * g + 0], yh[g].x, a);
                        a = fmaf(xr[4 * g + 1], yh[g].y, a);
                        a = fmaf(xr[4 * g + 2], yh[g].z, a);
                        a = fmaf(xr[4 * g + 3], yh[g].w, a);
                    }
                    acc[r] = a;
                }
            }
#pragma unroll
            for (int r = 0; r < RPW; ++r) {
                float t = fmaxf(fmaf(-2.f, acc[r], sqn[r] + sqm), 0.f);
                unsigned pk = (__float_as_uint(t) & 0xFFFFF000u) | (unsigned)m;
                insert32(list[r], pk, lane);
            }
        }
    }

#pragma unroll 1
    for (int r = 0; r < RPW; ++r)
        epilogue(list[r], rowbase + r, b, lane, pb, sqb, sqn[r], xyz, out);
}

extern "C" void kernel_launch(void* const* d_in, const int* in_sizes, int n_in,
                              void* d_out, int out_size, void* d_ws, size_t ws_size,
                              hipStream_t stream) {
    const float* xyz = (const float*)d_in[0];   // [8,4096,3]
    const float* pts = (const float*)d_in[1];   // [8,4096,64]
    float* sqw = (float*)d_ws;                  // 32768 floats = 128 KB scratch
    float* out = (float*)d_out;                 // [8,4096,16,10]

    sq_kernel<<<(NB * NPTS) / 256, 256, 0, stream>>>(pts, sqw);
    knn_kernel<<<NB * BPB, 256, 0, stream>>>(xyz, pts, sqw, out);
}

// Round 9
// 2969.435 us; speedup vs baseline: 1.3165x; 1.3165x over previous
//
#include <hip/hip_runtime.h>
#include <stdint.h>

typedef unsigned long long u64;

#define NB 8
#define NPTS 4096
#define NC 64
#define KOUT 16
#define TSEL 48          // fp32 preselect size (top-48 contains true top-32)
#define CHUNK 128
#define NCHUNK (NPTS / CHUNK)

// sq[p]: 8 accumulator chains over stride-8, separate mul/add roundings,
// combined ((r0+r1)+(r2+r3))+((r4+r5)+(r6+r7)).
// DO NOT CHANGE: verified bitwise model of the harness reference (R6 pass).
__global__ __launch_bounds__(256) void sq_kernel(const float* __restrict__ pts,
                                                 float* __restrict__ sqw) {
    int p = blockIdx.x * 256 + threadIdx.x;
    const float* r = pts + (size_t)p * NC;
    float acc[8];
#pragma unroll
    for (int j = 0; j < 8; ++j) acc[j] = __fmul_rn(r[j], r[j]);
#pragma unroll
    for (int i = 8; i < 64; i += 8)
#pragma unroll
        for (int j = 0; j < 8; ++j)
            acc[j] = __fadd_rn(acc[j], __fmul_rn(r[i + j], r[i + j]));
    float s01 = __fadd_rn(acc[0], acc[1]);
    float s23 = __fadd_rn(acc[2], acc[3]);
    float s45 = __fadd_rn(acc[4], acc[5]);
    float s67 = __fadd_rn(acc[6], acc[7]);
    sqw[p] = __fadd_rn(__fadd_rn(s01, s23), __fadd_rn(s45, s67));
}

// Ascending sorted 64-slot list, one u32/lane: (keybits & 0xFFFFF000) | idx.
// Threshold slot 47 (48th smallest). Stale-threshold over-insertion is safe
// (superset). 20-bit key quantization (~0.03) << rank-32->48 gap. u32 shfl
// = 1 bpermute (u64 was 2 -> was the whole SQ_LDS_BANK_CONFLICT signal).
// Validated in R8 (passed).
__device__ __forceinline__ void insert32(unsigned& list, unsigned cand, int lane) {
    unsigned thr = __shfl(list, 47);
    u64 mask = __ballot(cand < thr);
    while (mask) {
        int src = __ffsll(mask) - 1;
        unsigned v = __shfl(cand, src);
        int pos = __popcll(__ballot(list < v));
        unsigned up = __shfl_up(list, 1);
        list = (lane < pos) ? list : ((lane == pos) ? v : up);
        mask &= (mask - 1);
    }
}

// Exact re-rank of the 48 preselected candidates by the verified reference
// key: inner = ONE sequential FMA chain k=0..63 ascending;
// key = fl(fl(sq_n - fl(2*inner)) + sq_m); ties by index. DO NOT CHANGE.
__device__ __forceinline__ void epilogue(unsigned list, int n, int b, int lane,
                                         const float4 (&xq)[16],
                                         const float* __restrict__ pb,
                                         const float* __restrict__ sqb,
                                         float sqn,
                                         const float* __restrict__ xyz,
                                         float* __restrict__ out) {
    int m = (int)(list & 0xFFFu);
    const float4* yr = (const float4*)(pb + (size_t)m * NC);
    float4 yv[16];
#pragma unroll
    for (int i = 0; i < 16; ++i) yv[i] = yr[i];
    float acc = 0.f;
#pragma unroll
    for (int i = 0; i < 16; ++i) {
        acc = __fmaf_rn(xq[i].x, yv[i].x, acc);
        acc = __fmaf_rn(xq[i].y, yv[i].y, acc);
        acc = __fmaf_rn(xq[i].z, yv[i].z, acc);
        acc = __fmaf_rn(xq[i].w, yv[i].w, acc);
    }
    float key = __fadd_rn(__fsub_rn(sqn, __fmul_rn(2.0f, acc)), sqb[m]);

    int rank = 0;
#pragma unroll 1
    for (int j = 0; j < TSEL; ++j) {
        float kj = __shfl(key, j);
        int mj = __shfl(m, j);
        bool less = (kj < key) || (kj == key && mj < m);   // stable: lower idx first
        rank += less ? 1 : 0;
    }
    if (lane < TSEL && rank < 2 * KOUT && (rank & 1) == 0) {  // dilation D=2
        int k = rank >> 1;
        const float* xn = xyz + ((size_t)b * NPTS + n) * 3;
        const float* xm = xyz + ((size_t)b * NPTS + m) * 3;
        float xnx = xn[0], xny = xn[1], xnz = xn[2];
        float ox = xm[0], oy = xm[1], oz = xm[2];
        float rx = xnx - ox, ry = xny - oy, rz = xnz - oz;
        float dis = sqrtf(rx * rx + ry * ry + rz * rz);
        float* o = out + (((size_t)b * NPTS + n) * KOUT + k) * 10;
        o[0] = dis; o[1] = rx; o[2] = ry; o[3] = rz;
        o[4] = xnx; o[5] = xny; o[6] = xnz;
        o[7] = ox;  o[8] = oy;  o[9] = oz;
    }
}

// R6 structure: wave owns 2 query rows (x resident in 128 VGPRs), lane |->
// candidate. XOR-swizzled y tile (phys slot q of row ml holds logical
// q ^ (ml & 15)) — measured conflict-free in R8. __launch_bounds__(256,1)
// unlocks the 256-VGPR budget: ~190 live regs, NO spills (R6's 1.5 GB
// WRITE_SIZE was spill traffic from the compiler's 128-VGPR cap).
__global__ __launch_bounds__(256, 1)
void knn_kernel(const float* __restrict__ xyz,
                const float* __restrict__ pts,
                const float* __restrict__ sqw,
                float* __restrict__ out) {

    __shared__ float4 ylds[CHUNK * 16];   // 32 KB

    const int tid = threadIdx.x;
    const int lane = tid & 63;
    const int wave = tid >> 6;
    const int sw = lane & 15;
    const int b = blockIdx.x >> 9;                  // 512 blocks per batch
    const int rowbase = (blockIdx.x & 511) << 3;    // 8 rows per block
    const int n0 = rowbase + wave * 2;
    const int n1 = n0 + 1;
    const float* pb = pts + (size_t)b * NPTS * NC;
    const float* sqb = sqw + (size_t)b * NPTS;

    // x-features for the wave's two rows, replicated per lane (logical order)
    float4 x0q[16], x1q[16];
    {
        const float4* xr0 = (const float4*)(pb + (size_t)n0 * NC);
        const float4* xr1 = (const float4*)(pb + (size_t)n1 * NC);
#pragma unroll
        for (int i = 0; i < 16; ++i) { x0q[i] = xr0[i]; x1q[i] = xr1[i]; }
    }
    const float sqn0 = sqb[n0];
    const float sqn1 = sqb[n1];

    unsigned list0 = 0xFFFFFFFFu, list1 = 0xFFFFFFFFu;

    const float4* gsrc = (const float4*)pb;
    float4 pf[8];
#pragma unroll
    for (int j = 0; j < 8; ++j) pf[j] = gsrc[tid + 256 * j];   // prefetch chunk 0

    for (int c = 0; c < NCHUNK; ++c) {
        __syncthreads();   // previous chunk fully consumed
#pragma unroll
        for (int j = 0; j < 8; ++j) {
            int s = tid + 256 * j;
            int ml = s >> 4;
            int c4 = s & 15;
            ylds[ml * 16 + (c4 ^ (ml & 15))] = pf[j];   // swizzled store
        }
        __syncthreads();
        if (c + 1 < NCHUNK) {
#pragma unroll
            for (int j = 0; j < 8; ++j)
                pf[j] = gsrc[(size_t)(c + 1) * (CHUNK * 16) + tid + 256 * j];
        }
#pragma unroll
        for (int jm = 0; jm < 2; ++jm) {
            const int ml = lane + 64 * jm;
            const int m = c * CHUNK + ml;
            const float4* yrow = &ylds[ml * 16];
            float a0x = 0.f, a0y = 0.f, a0z = 0.f, a0w = 0.f;
            float a1x = 0.f, a1y = 0.f, a1z = 0.f, a1w = 0.f;
#pragma unroll
            for (int p = 0; p < 16; ++p) {
                float4 y = yrow[p ^ sw];    // swizzled read -> logical slot p
                a0x = fmaf(x0q[p].x, y.x, a0x);
                a0y = fmaf(x0q[p].y, y.y, a0y);
                a0z = fmaf(x0q[p].z, y.z, a0z);
                a0w = fmaf(x0q[p].w, y.w, a0w);
                a1x = fmaf(x1q[p].x, y.x, a1x);
                a1y = fmaf(x1q[p].y, y.y, a1y);
                a1z = fmaf(x1q[p].z, y.z, a1z);
                a1w = fmaf(x1q[p].w, y.w, a1w);
            }
            float ip0 = (a0x + a0y) + (a0z + a0w);
            float ip1 = (a1x + a1y) + (a1z + a1w);
            float sqm = sqb[m];
            // approx preselect key; exact ranking happens in the epilogue
            float t0 = fmaxf(fmaf(-2.f, ip0, sqn0 + sqm), 0.f);
            float t1 = fmaxf(fmaf(-2.f, ip1, sqn1 + sqm), 0.f);
            unsigned pk0 = (__float_as_uint(t0) & 0xFFFFF000u) | (unsigned)m;
            unsigned pk1 = (__float_as_uint(t1) & 0xFFFFF000u) | (unsigned)m;
            insert32(list0, pk0, lane);
            insert32(list1, pk1, lane);
        }
    }

    epilogue(list0, n0, b, lane, x0q, pb, sqb, sqn0, xyz, out);
    epilogue(list1, n1, b, lane, x1q, pb, sqb, sqn1, xyz, out);
}

extern "C" void kernel_launch(void* const* d_in, const int* in_sizes, int n_in,
                              void* d_out, int out_size, void* d_ws, size_t ws_size,
                              hipStream_t stream) {
    const float* xyz = (const float*)d_in[0];   // [8,4096,3]
    const float* pts = (const float*)d_in[1];   // [8,4096,64]
    float* sqw = (float*)d_ws;                  // 32768 floats = 128 KB scratch
    float* out = (float*)d_out;                 // [8,4096,16,10]

    sq_kernel<<<(NB * NPTS) / 256, 256, 0, stream>>>(pts, sqw);
    knn_kernel<<<(NB * NPTS) / 8, 256, 0, stream>>>(xyz, pts, sqw, out);
}

// Round 11
// 2245.568 us; speedup vs baseline: 1.7409x; 1.3224x over previous
//
#include <hip/hip_runtime.h>
#include <stdint.h>

typedef unsigned long long u64;
typedef __fp16 h2 __attribute__((ext_vector_type(2)));
typedef _Float16 f16x2 __attribute__((ext_vector_type(2)));

#define NB 8
#define NPTS 4096
#define NC 64
#define KOUT 16
#define TSEL 48          // preselect size (top-48 contains true top-32)
#define CHUNK 128
#define NCHUNK (NPTS / CHUNK)
#define LTOP 12          // per-lane local list depth

__device__ __forceinline__ float DOT2(h2 a, h2 b, float c) {
#if __has_builtin(__builtin_amdgcn_fdot2)
    return __builtin_amdgcn_fdot2(__builtin_bit_cast(f16x2, a),
                                  __builtin_bit_cast(f16x2, b), c, false);
#else
    c = fmaf((float)a.x, (float)b.x, c);
    return fmaf((float)a.y, (float)b.y, c);
#endif
}

// sq[p]: 8 accumulator chains over stride-8, separate mul/add roundings,
// combined ((r0+r1)+(r2+r3))+((r4+r5)+(r6+r7)).
// DO NOT CHANGE: verified bitwise model of the harness reference (R6 pass).
__global__ __launch_bounds__(256) void sq_kernel(const float* __restrict__ pts,
                                                 float* __restrict__ sqw) {
    int p = blockIdx.x * 256 + threadIdx.x;
    const float* r = pts + (size_t)p * NC;
    float acc[8];
#pragma unroll
    for (int j = 0; j < 8; ++j) acc[j] = __fmul_rn(r[j], r[j]);
#pragma unroll
    for (int i = 8; i < 64; i += 8)
#pragma unroll
        for (int j = 0; j < 8; ++j)
            acc[j] = __fadd_rn(acc[j], __fmul_rn(r[i + j], r[i + j]));
    float s01 = __fadd_rn(acc[0], acc[1]);
    float s23 = __fadd_rn(acc[2], acc[3]);
    float s45 = __fadd_rn(acc[4], acc[5]);
    float s67 = __fadd_rn(acc[6], acc[7]);
    sqw[p] = __fadd_rn(__fadd_rn(s01, s23), __fadd_rn(s45, s67));
}

// Per-lane sorted top-12 insert. Lanes with pk >= l[11] run the chain as a
// provable no-op (min(pk,l[j])=l[j] -> l[j]=max(l[j-1],l[j])=l[j]).
__device__ __forceinline__ void filter12(unsigned (&l)[LTOP], unsigned pk) {
    if (__ballot(pk < l[LTOP - 1])) {
#pragma unroll
        for (int j = LTOP - 1; j >= 1; --j)
            l[j] = max(l[j - 1], min(pk, l[j]));   // med3(pk, l[j-1], l[j])
        l[0] = min(l[0], pk);
    }
}

// Bitonic full sort of one u32 per lane, ascending by lane id.
__device__ __forceinline__ unsigned sort64(unsigned v, int lane) {
#pragma unroll
    for (int k = 2; k <= 64; k <<= 1) {
#pragma unroll
        for (int j = k >> 1; j > 0; j >>= 1) {
            unsigned o = (unsigned)__shfl_xor((int)v, j);
            bool takemax = ((lane & j) != 0) == ((lane & k) == 0);
            unsigned mn = min(v, o), mx = max(v, o);
            v = takemax ? mx : mn;
        }
    }
    return v;
}

// Merge per-lane sorted top-12 lists into a lane-sorted global 64-list whose
// first 48 slots are the row's approx-top-48. Early exit: lists are per-lane
// ascending and the slot-47 threshold only decreases, so an empty round
// implies all later rounds are empty.
__device__ __forceinline__ unsigned merge_rounds(const unsigned (&l)[LTOP], int lane) {
    unsigned v = sort64(l[0], lane);
    bool done = false;
#pragma unroll
    for (int j = 1; j < LTOP; ++j) {
        if (!done) {
            unsigned thr = (unsigned)__shfl((int)v, 47);
            unsigned cand = l[j];
            u64 mask = __ballot(cand < thr);
            if (!mask) done = true;
            while (mask) {
                int src = __ffsll(mask) - 1;
                unsigned val = (unsigned)__shfl((int)cand, src);
                int pos = __popcll(__ballot(v < val));
                unsigned up = (unsigned)__shfl_up((int)v, 1);
                v = (lane < pos) ? v : ((lane == pos) ? val : up);
                mask &= (mask - 1);
            }
        }
    }
    return v;
}

// Exact re-rank of the 48 preselected candidates by the verified reference
// key: inner = ONE sequential FMA chain k=0..63 ascending (fp32 x,y from
// global); key = fl(fl(sq_n - fl(2*inner)) + sq_m); ties by index.
// DO NOT CHANGE the arithmetic.
__device__ __forceinline__ void epilogue(unsigned list, int n, int b, int lane,
                                         const float* __restrict__ pb,
                                         const float* __restrict__ sqb,
                                         float sqn,
                                         const float* __restrict__ xyz,
                                         float* __restrict__ out) {
    int m = (int)(list & 0xFFFu);
    const float4* yr = (const float4*)(pb + (size_t)m * NC);
    const float4* xr = (const float4*)(pb + (size_t)n * NC);
    float acc = 0.f;
#pragma unroll
    for (int i = 0; i < 16; ++i) {
        float4 yv = yr[i];
        float4 xv = xr[i];
        acc = __fmaf_rn(xv.x, yv.x, acc);
        acc = __fmaf_rn(xv.y, yv.y, acc);
        acc = __fmaf_rn(xv.z, yv.z, acc);
        acc = __fmaf_rn(xv.w, yv.w, acc);
    }
    float key = __fadd_rn(__fsub_rn(sqn, __fmul_rn(2.0f, acc)), sqb[m]);

    int rank = 0;
#pragma unroll 1
    for (int j = 0; j < TSEL; ++j) {
        float kj = __shfl(key, j);
        int mj = __shfl(m, j);
        bool less = (kj < key) || (kj == key && mj < m);   // stable: lower idx first
        rank += less ? 1 : 0;
    }
    if (lane < TSEL && rank < 2 * KOUT && (rank & 1) == 0) {  // dilation D=2
        int k = rank >> 1;
        const float* xn = xyz + ((size_t)b * NPTS + n) * 3;
        const float* xm = xyz + ((size_t)b * NPTS + m) * 3;
        float xnx = xn[0], xny = xn[1], xnz = xn[2];
        float ox = xm[0], oy = xm[1], oz = xm[2];
        float rx = xnx - ox, ry = xny - oy, rz = xnz - oz;
        float dis = sqrtf(rx * rx + ry * ry + rz * rz);
        float* o = out + (((size_t)b * NPTS + n) * KOUT + k) * 10;
        o[0] = dis; o[1] = rx; o[2] = ry; o[3] = rz;
        o[4] = xnx; o[5] = xny; o[6] = xnz;
        o[7] = ox;  o[8] = oy;  o[9] = oz;
    }
}

// Wave owns 2 rows (x as packed f16: 64 VGPR). lane |-> candidate. y staged
// fp32 via async global_load_lds with the XOR swizzle applied on the SOURCE
// address (per-16-lane it permutes within one 256B row -> still coalesced;
// LDS dest is base + lane*16 as HW requires). Preselect key via
// v_dot2_f32_f16 (fp32 accum; ~1e-2 accurate << O(1) rank-32->48 margin).
__global__ __launch_bounds__(256, 4)
void knn_kernel(const float* __restrict__ xyz,
                const float* __restrict__ pts,
                const float* __restrict__ sqw,
                float* __restrict__ out) {

    __shared__ float4 ylds[CHUNK * 16];   // 32 KB

    const int tid = threadIdx.x;
    const int lane = tid & 63;
    const int wave = tid >> 6;
    const int sw = lane & 15;
    const int b = blockIdx.x >> 9;                  // 512 blocks per batch
    const int rowbase = (blockIdx.x & 511) << 3;    // 8 rows per block
    const int n0 = rowbase + wave * 2;
    const int n1 = n0 + 1;
    const float* pb = pts + (size_t)b * NPTS * NC;
    const float* sqb = sqw + (size_t)b * NPTS;

    // x rows as packed f16 (32 regs each)
    h2 x0h[32], x1h[32];
    {
        const float4* xr0 = (const float4*)(pb + (size_t)n0 * NC);
        const float4* xr1 = (const float4*)(pb + (size_t)n1 * NC);
#pragma unroll
        for (int i = 0; i < 16; ++i) {
            float4 v0 = xr0[i], v1 = xr1[i];
            x0h[2 * i] = __builtin_amdgcn_cvt_pkrtz(v0.x, v0.y);
            x0h[2 * i + 1] = __builtin_amdgcn_cvt_pkrtz(v0.z, v0.w);
            x1h[2 * i] = __builtin_amdgcn_cvt_pkrtz(v1.x, v1.y);
            x1h[2 * i + 1] = __builtin_amdgcn_cvt_pkrtz(v1.z, v1.w);
        }
    }
    const float sqn0 = sqb[n0];
    const float sqn1 = sqb[n1];

    unsigned l0[LTOP], l1[LTOP];
#pragma unroll
    for (int j = 0; j < LTOP; ++j) { l0[j] = 0xFFFFFFFFu; l1[j] = 0xFFFFFFFFu; }

    const int t4 = wave * 8;   // this wave stages LDS float4 [t4*64, t4*64+512)

    for (int c = 0; c < NCHUNK; ++c) {
        __syncthreads();   // previous chunk fully consumed
#pragma unroll
        for (int t = 0; t < 8; ++t) {
            int rr = (t4 + t) * 4 + (lane >> 4);           // chunk row 0..127
            int cc = (lane & 15) ^ (rr & 15);              // swizzled source col
            const float* gp = pb + (size_t)(c * CHUNK + rr) * NC + cc * 4;
            __builtin_amdgcn_global_load_lds(
                (const __attribute__((address_space(1))) void*)gp,
                (__attribute__((address_space(3))) void*)&ylds[(t4 + t) * 64 + lane],
                16, 0, 0);
        }
        __syncthreads();   // compiler emits vmcnt(0) drain before barrier
#pragma unroll
        for (int sc = 0; sc < 2; ++sc) {
            const int crow = sc * 64 + lane;
            const int m = c * CHUNK + crow;
            const float sqm = sqb[m];
            const float4* yrow = &ylds[crow * 16];
            float a00 = 0.f, a01 = 0.f, a10 = 0.f, a11 = 0.f;
#pragma unroll
            for (int p = 0; p < 16; ++p) {
                float4 y = yrow[p ^ sw];    // swizzled read -> logical slot p
                h2 hy0 = __builtin_amdgcn_cvt_pkrtz(y.x, y.y);
                h2 hy1 = __builtin_amdgcn_cvt_pkrtz(y.z, y.w);
                a00 = DOT2(x0h[2 * p], hy0, a00);
                a01 = DOT2(x0h[2 * p + 1], hy1, a01);
                a10 = DOT2(x1h[2 * p], hy0, a10);
                a11 = DOT2(x1h[2 * p + 1], hy1, a11);
            }
            float t0 = fmaxf(fmaf(-2.f, a00 + a01, sqn0 + sqm), 0.f);
            float t1 = fmaxf(fmaf(-2.f, a10 + a11, sqn1 + sqm), 0.f);
            filter12(l0, (__float_as_uint(t0) & 0xFFFFF000u) | (unsigned)m);
            filter12(l1, (__float_as_uint(t1) & 0xFFFFF000u) | (unsigned)m);
        }
    }

    unsigned list0 = merge_rounds(l0, lane);
    unsigned list1 = merge_rounds(l1, lane);

    epilogue(list0, n0, b, lane, pb, sqb, sqn0, xyz, out);
    epilogue(list1, n1, b, lane, pb, sqb, sqn1, xyz, out);
}

extern "C" void kernel_launch(void* const* d_in, const int* in_sizes, int n_in,
                              void* d_out, int out_size, void* d_ws, size_t ws_size,
                              hipStream_t stream) {
    const float* xyz = (const float*)d_in[0];   // [8,4096,3]
    const float* pts = (const float*)d_in[1];   // [8,4096,64]
    float* sqw = (float*)d_ws;                  // 32768 floats = 128 KB scratch
    float* out = (float*)d_out;                 // [8,4096,16,10]

    sq_kernel<<<(NB * NPTS) / 256, 256, 0, stream>>>(pts, sqw);
    knn_kernel<<<(NB * NPTS) / 8, 256, 0, stream>>>(xyz, pts, sqw, out);
}